// Round 1
// baseline (219.593 us; speedup 1.0000x reference)
//
#include <hip/hip_runtime.h>
#include <math.h>

#define Bb 256
#define Nn 256
#define Dd 512
#define Cc 1024
#define KC 8          // split-K chunks in logits
#define KD (Dd / KC)  // 64 d per chunk
#define BT 8          // b-tile in logits

__device__ __forceinline__ float waveReduceSum(float v) {
    #pragma unroll
    for (int off = 32; off > 0; off >>= 1)
        v += __shfl_xor(v, off, 64);
    return v;
}
__device__ __forceinline__ float waveReduceMax(float v) {
    #pragma unroll
    for (int off = 32; off > 0; off >>= 1)
        v = fmaxf(v, __shfl_xor(v, off, 64));
    return v;
}

// A (fused norm + transpose): txt [C,D] -> txt_t [D,C] with L2-normalized rows.
// grid = (C/32, D/128), 256 threads. Norm is recomputed per d-slice (4x redundant,
// cheap: 64 KB/block) to keep 128 blocks of parallelism.
__global__ void k_txt_prep(const float* __restrict__ txt, float* __restrict__ txt_t) {
    __shared__ float ssp[32][8];
    __shared__ float inv[32];
    __shared__ float tile[32][33];
    const int c0 = blockIdx.x * 32;
    const int t = threadIdx.x;
    // phase A: sum of squares for 32 rows; 8 threads per row, 64 elems each
    {
        const int r = t >> 3, seg = t & 7;
        const float4* p = (const float4*)(txt + (size_t)(c0 + r) * Dd + seg * 64);
        float s = 0.f;
        #pragma unroll
        for (int i = 0; i < 16; ++i) {
            const float4 a = p[i];
            s += a.x*a.x + a.y*a.y + a.z*a.z + a.w*a.w;
        }
        ssp[r][seg] = s;
    }
    __syncthreads();
    if (t < 32) {
        float s = 0.f;
        #pragma unroll
        for (int j = 0; j < 8; ++j) s += ssp[t][j];
        inv[t] = 1.0f / fmaxf(sqrtf(s), 1e-12f);
    }
    __syncthreads();
    // phase C: transpose this block's 128-d slice, scaling by inv
    const int dx = t & 31, r4 = t >> 5;
    const int dt0 = blockIdx.y * 128;
    for (int dt = dt0; dt < dt0 + 128; dt += 32) {
        #pragma unroll
        for (int rr = r4; rr < 32; rr += 8)
            tile[rr][dx] = txt[(size_t)(c0 + rr) * Dd + dt + dx] * inv[rr];
        __syncthreads();
        #pragma unroll
        for (int rr = r4; rr < 32; rr += 8)
            txt_t[(size_t)(dt + rr) * Cc + c0 + dx] = tile[dx][rr];
        __syncthreads();
    }
}

// B (fused simgt+softmax+qpart): ONE pass over tokens with online softmax.
// grid = B blocks, 1024 threads (16 waves, 16 rows each), rows in batches of 4
// with ILP'd butterfly reductions + 4-row prefetch.
// q[b][d] = sum_n softmax_n(sims_gt/at) * invn_n * tok[b][n][d]
__global__ void __launch_bounds__(1024) k_attn_q(const float* __restrict__ toks,
                                                 const float* __restrict__ txt,
                                                 const int* __restrict__ pid,
                                                 const float* __restrict__ log_attn_tau,
                                                 float* __restrict__ q) {
    const int b = blockIdx.x;
    const int tid = threadIdx.x;
    const int wv = tid >> 6;     // 0..15
    const int lane = tid & 63;
    __shared__ float xg[Dd];
    __shared__ float r8[8];
    __shared__ float qpart_s[16][Dd];   // 32 KB
    __shared__ float ms[16], Ss[16];

    // phase 0: normalize text row g in-block (from raw txt)
    const int g = pid[b];
    float v = 0.f;
    if (tid < Dd) v = txt[(size_t)g * Dd + tid];
    float p = v * v;
    p = waveReduceSum(p);
    if (lane == 0 && wv < 8) r8[wv] = p;
    __syncthreads();
    const float tot = r8[0]+r8[1]+r8[2]+r8[3]+r8[4]+r8[5]+r8[6]+r8[7];
    const float invg = 1.0f / fmaxf(sqrtf(tot), 1e-12f);
    if (tid < Dd) xg[tid] = v * invg;
    __syncthreads();

    float at = expf(log_attn_tau[0]);
    at = fminf(fmaxf(at, 0.01f), 1.0f);
    const float iat = 1.0f / at;

    const float4 xg0 = *(const float4*)&xg[lane * 8];
    const float4 xg1 = *(const float4*)&xg[lane * 8 + 4];

    float m = -INFINITY, S = 0.0f;
    float qa[8] = {0.f, 0.f, 0.f, 0.f, 0.f, 0.f, 0.f, 0.f};

    const float* base = toks + ((size_t)b * Nn + wv * 16) * Dd + (size_t)lane * 8;
    float4 c0[4], c1[4];
    #pragma unroll
    for (int k = 0; k < 4; ++k) {
        c0[k] = *(const float4*)(base + k * Dd);
        c1[k] = *(const float4*)(base + k * Dd + 4);
    }
    #pragma unroll
    for (int batch = 0; batch < 4; ++batch) {
        float4 n0[4], n1[4];
        if (batch < 3) {   // prefetch next 4 rows
            const float* pn = base + (batch + 1) * 4 * Dd;
            #pragma unroll
            for (int k = 0; k < 4; ++k) {
                n0[k] = *(const float4*)(pn + k * Dd);
                n1[k] = *(const float4*)(pn + k * Dd + 4);
            }
        }
        float dt[4], ss[4];
        #pragma unroll
        for (int k = 0; k < 4; ++k) {
            dt[k] = c0[k].x*xg0.x + c0[k].y*xg0.y + c0[k].z*xg0.z + c0[k].w*xg0.w
                  + c1[k].x*xg1.x + c1[k].y*xg1.y + c1[k].z*xg1.z + c1[k].w*xg1.w;
            ss[k] = c0[k].x*c0[k].x + c0[k].y*c0[k].y + c0[k].z*c0[k].z + c0[k].w*c0[k].w
                  + c1[k].x*c1[k].x + c1[k].y*c1[k].y + c1[k].z*c1[k].z + c1[k].w*c1[k].w;
        }
        // 8 interleaved butterflies: shuffle latency hidden by ILP
        #pragma unroll
        for (int off = 32; off > 0; off >>= 1) {
            #pragma unroll
            for (int k = 0; k < 4; ++k) {
                dt[k] += __shfl_xor(dt[k], off, 64);
                ss[k] += __shfl_xor(ss[k], off, 64);
            }
        }
        #pragma unroll
        for (int k = 0; k < 4; ++k) {
            const float inv = 1.0f / fmaxf(sqrtf(ss[k]), 1e-12f);
            const float s = dt[k] * inv;   // lane-invariant -> wave-uniform branch
            if (s > m) {
                const float sc = expf((m - s) * iat);   // first row: exp(-inf)=0
                S = S * sc + 1.0f;
                qa[0] = qa[0]*sc + inv*c0[k].x; qa[1] = qa[1]*sc + inv*c0[k].y;
                qa[2] = qa[2]*sc + inv*c0[k].z; qa[3] = qa[3]*sc + inv*c0[k].w;
                qa[4] = qa[4]*sc + inv*c1[k].x; qa[5] = qa[5]*sc + inv*c1[k].y;
                qa[6] = qa[6]*sc + inv*c1[k].z; qa[7] = qa[7]*sc + inv*c1[k].w;
                m = s;
            } else {
                const float e = expf((s - m) * iat);
                S += e;
                const float w = e * inv;
                qa[0] = fmaf(w, c0[k].x, qa[0]); qa[1] = fmaf(w, c0[k].y, qa[1]);
                qa[2] = fmaf(w, c0[k].z, qa[2]); qa[3] = fmaf(w, c0[k].w, qa[3]);
                qa[4] = fmaf(w, c1[k].x, qa[4]); qa[5] = fmaf(w, c1[k].y, qa[5]);
                qa[6] = fmaf(w, c1[k].z, qa[6]); qa[7] = fmaf(w, c1[k].w, qa[7]);
            }
        }
        #pragma unroll
        for (int k = 0; k < 4; ++k) { c0[k] = n0[k]; c1[k] = n1[k]; }
    }
    #pragma unroll
    for (int j = 0; j < 8; ++j) qpart_s[wv][lane * 8 + j] = qa[j];
    if (lane == 0) { ms[wv] = m; Ss[wv] = S; }
    __syncthreads();
    if (tid < Dd) {
        float M = -INFINITY;
        #pragma unroll
        for (int w = 0; w < 16; ++w) M = fmaxf(M, ms[w]);
        float Stot = 0.f, acc = 0.f;
        #pragma unroll
        for (int w = 0; w < 16; ++w) {
            const float sc = expf((ms[w] - M) * iat);
            Stot = fmaf(Ss[w], sc, Stot);
            acc = fmaf(qpart_s[w][tid], sc, acc);
        }
        q[(size_t)b * Dd + tid] = acc / Stot;
    }
}

// E: split-K logits partials, b-tile=8. grid = (B/8, KC), 256 threads.
// part[kc][b][c] = sum_{d in chunk} q[b][d] * txt_t[d][c]
__global__ void k_logits(const float* __restrict__ q, const float* __restrict__ txt_t,
                         float* __restrict__ part) {
    const int b0 = blockIdx.x * BT;
    const int kc = blockIdx.y;
    const int d0 = kc * KD;
    const int t = threadIdx.x;     // 4 c's each (float4), 1024 c total
    __shared__ float qs[BT][KD];
    for (int i = t; i < BT * KD; i += 256)
        qs[i >> 6][i & 63] = q[(size_t)(b0 + (i >> 6)) * Dd + d0 + (i & 63)];
    __syncthreads();
    const float4* xt = (const float4*)txt_t;   // [D][C/4]
    float4 a[BT];
    #pragma unroll
    for (int j = 0; j < BT; ++j) a[j] = make_float4(0.f, 0.f, 0.f, 0.f);
    #pragma unroll 2
    for (int d = 0; d < KD; d += 4) {
        const float4 x0 = xt[(size_t)(d0 + d + 0) * (Cc / 4) + t];
        const float4 x1 = xt[(size_t)(d0 + d + 1) * (Cc / 4) + t];
        const float4 x2 = xt[(size_t)(d0 + d + 2) * (Cc / 4) + t];
        const float4 x3 = xt[(size_t)(d0 + d + 3) * (Cc / 4) + t];
        #pragma unroll
        for (int j = 0; j < BT; ++j) {
            const float4 qj = *(const float4*)&qs[j][d];   // lane-uniform LDS broadcast
            a[j].x = fmaf(qj.x,x0.x,a[j].x); a[j].y = fmaf(qj.x,x0.y,a[j].y); a[j].z = fmaf(qj.x,x0.z,a[j].z); a[j].w = fmaf(qj.x,x0.w,a[j].w);
            a[j].x = fmaf(qj.y,x1.x,a[j].x); a[j].y = fmaf(qj.y,x1.y,a[j].y); a[j].z = fmaf(qj.y,x1.z,a[j].z); a[j].w = fmaf(qj.y,x1.w,a[j].w);
            a[j].x = fmaf(qj.z,x2.x,a[j].x); a[j].y = fmaf(qj.z,x2.y,a[j].y); a[j].z = fmaf(qj.z,x2.z,a[j].z); a[j].w = fmaf(qj.z,x2.w,a[j].w);
            a[j].x = fmaf(qj.w,x3.x,a[j].x); a[j].y = fmaf(qj.w,x3.y,a[j].y); a[j].z = fmaf(qj.w,x3.z,a[j].z); a[j].w = fmaf(qj.w,x3.w,a[j].w);
        }
    }
    float* pb = part + ((size_t)kc * Bb + b0) * Cc;
    #pragma unroll
    for (int j = 0; j < BT; ++j) ((float4*)(pb + (size_t)j * Cc))[t] = a[j];
}

// E2: sum K-partials, scale by 1/tau, LSE + NLL. grid = B blocks, 256 threads.
__global__ void k_lse(const float* __restrict__ part, const int* __restrict__ pid,
                      const float* __restrict__ log_tau, float* __restrict__ nll) {
    const int b = blockIdx.x;
    const int t = threadIdx.x;   // 4 c's each
    float4 l = {0,0,0,0};
    #pragma unroll
    for (int kc = 0; kc < KC; ++kc) {
        const float4 p = ((const float4*)(part + ((size_t)kc * Bb + b) * Cc))[t];
        l.x += p.x; l.y += p.y; l.z += p.z; l.w += p.w;
    }
    float tau = expf(log_tau[0]);
    tau = fminf(fmaxf(tau, 0.01f), 1.0f);
    const float itau = 1.0f / tau;
    l.x *= itau; l.y *= itau; l.z *= itau; l.w *= itau;

    const int g = pid[b];
    __shared__ float redm[4], reds[4], sgt;
    if ((g >> 2) == t) {
        const float v[4] = {l.x, l.y, l.z, l.w};
        sgt = v[g & 3];
    }
    float m = fmaxf(fmaxf(l.x, l.y), fmaxf(l.z, l.w));
    m = waveReduceMax(m);
    if ((t & 63) == 0) redm[t >> 6] = m;
    __syncthreads();
    m = fmaxf(fmaxf(redm[0], redm[1]), fmaxf(redm[2], redm[3]));
    float e = expf(l.x - m) + expf(l.y - m) + expf(l.z - m) + expf(l.w - m);
    e = waveReduceSum(e);
    if ((t & 63) == 0) reds[t >> 6] = e;
    __syncthreads();
    if (t == 0) {
        const float S = reds[0] + reds[1] + reds[2] + reds[3];
        nll[b] = m + logf(S) - sgt;
    }
}

// F: mean over B. 1 block, 256 threads.
__global__ void k_mean(const float* __restrict__ nll, float* __restrict__ out) {
    float v = nll[threadIdx.x];
    __shared__ float red[4];
    v = waveReduceSum(v);
    if ((threadIdx.x & 63) == 0) red[threadIdx.x >> 6] = v;
    __syncthreads();
    if (threadIdx.x == 0) out[0] = (red[0] + red[1] + red[2] + red[3]) * (1.0f / (float)Bb);
}

extern "C" void kernel_launch(void* const* d_in, const int* in_sizes, int n_in,
                              void* d_out, int out_size, void* d_ws, size_t ws_size,
                              hipStream_t stream) {
    const float* toks = (const float*)d_in[0];     // [B,N,D] fp32
    const float* txt = (const float*)d_in[1];      // [C,D] fp32
    const float* log_tau = (const float*)d_in[2];
    const float* log_attn_tau = (const float*)d_in[3];
    const int* pid = (const int*)d_in[4];          // [B] int32
    float* out = (float*)d_out;

    float* ws = (float*)d_ws;
    float* txt_t = ws;                             // D*C
    float* q     = txt_t + (size_t)Dd * Cc;        // B*D
    float* part  = q + (size_t)Bb * Dd;            // KC*B*C
    float* nll   = part + (size_t)KC * Bb * Cc;    // B

    k_txt_prep<<<dim3(Cc / 32, Dd / 128), 256, 0, stream>>>(txt, txt_t);
    k_attn_q<<<Bb, 1024, 0, stream>>>(toks, txt, pid, log_attn_tau, q);
    k_logits<<<dim3(Bb / BT, KC), 256, 0, stream>>>(q, txt_t, part);
    k_lse<<<Bb, 256, 0, stream>>>(part, pid, log_tau, nll);
    k_mean<<<1, 256, 0, stream>>>(nll, out);
}